// Round 9
// baseline (372.251 us; speedup 1.0000x reference)
//
#include <hip/hip_runtime.h>
#include <hip/hip_bf16.h>
#include <stdint.h>

#define MM 16384
#define DD 256
#define HH 4
#define KK 16
#define DFF_ 1024

typedef __attribute__((ext_vector_type(8))) short bf16x8;
typedef __attribute__((ext_vector_type(16))) float f32x16;
typedef __attribute__((ext_vector_type(2))) float f32x2;

__device__ __forceinline__ unsigned short f2bf(float f) {
    unsigned u = __builtin_bit_cast(unsigned, f);
    unsigned r = u + 0x7fffu + ((u >> 16) & 1u);
    return (unsigned short)(r >> 16);
}
__device__ __forceinline__ float bf2f(unsigned short h) {
    unsigned u = ((unsigned)h) << 16;
    return __builtin_bit_cast(float, u);
}

// Async global->LDS, 16B per lane: lane i's 16B lands at lds_base + i*16.
__device__ __forceinline__ void gload_lds16(const void* g, void* l) {
    __builtin_amdgcn_global_load_lds(
        (__attribute__((address_space(1))) void*)(void*)g,
        (__attribute__((address_space(3))) void*)l, 16, 0, 0);
}

// ---------------------------------------------------------------------------
// Fragment layouts (bf16, 16B chunks of 8 elems):
// A-frag (row m, k):  chunk = ((m>>5)*(KD/16) + (k>>4))*64 + ((k>>3)&1)*32 + (m&31), elem = k&7
// B-frag (col n, k):  same with n.
// v_mfma_f32_32x32x16_bf16 C/D: col=lane&31, row=(reg&3)+8*(reg>>2)+4*(lane>>5)
// kv buffer: fp8 e4m3 rows of 512 B, groups of 8 B = [K4 | V4].
// NOTE (R4): 64x128 wave tiles (acc[2][4]) spill -> keep 64x64 (acc[2][2]).
// NOTE (R5): gelu: sigmoid form + pad-33 LDS + no barriers.
// NOTE (R6): full-row LN fusion (1 wg/CU) regressed; reverted.
// NOTE (R8): GEMMs were latency-bound (Mfma 4%, occ 25%, no staging). This
//   round: m97-style global_load_lds double-buffered staging, BK=64,
//   4 waves = 2m x 2k, split-K reduce aliased onto staging LDS.
// ---------------------------------------------------------------------------

// wfrag layout (shorts): WQF@0 (blk stride 65536), KVF@131072 (131072),
//   WOF@393216 (65536), W1F@524288 (262144), W2F@1048576 (262144)
__global__ __launch_bounds__(256) void prep_weights(
        const float* __restrict__ Wq, const float* __restrict__ Wk,
        const float* __restrict__ Wv, const float* __restrict__ Wo,
        const float* __restrict__ W1, const float* __restrict__ W2,
        unsigned short* __restrict__ wf) {
    int t = blockIdx.x * blockDim.x + threadIdx.x;
    const float* src; unsigned short* dst;
    int kd, lg, rem, blk, e, sect;
    if (t < 131072) { sect = 0; rem = t; blk = rem >> 16; e = rem & 65535;
        src = Wq; dst = wf + blk * 65536; kd = 256; lg = 8; }
    else if (t < 262144) { sect = 1; rem = t - 131072; blk = rem >> 16; e = rem & 65535;
        src = Wk; dst = wf + 131072 + blk * 131072; kd = 256; lg = 8; }
    else if (t < 393216) { sect = 2; rem = t - 262144; blk = rem >> 16; e = rem & 65535;
        src = Wv; dst = wf + 131072 + blk * 131072; kd = 256; lg = 8; }
    else if (t < 524288) { sect = 0; rem = t - 393216; blk = rem >> 16; e = rem & 65535;
        src = Wo; dst = wf + 393216 + blk * 65536; kd = 256; lg = 8; }
    else if (t < 1048576) { sect = 0; rem = t - 524288; blk = rem >> 18; e = rem & 262143;
        src = W1; dst = wf + 524288 + blk * 262144; kd = 256; lg = 10; }
    else if (t < 1572864) { sect = 0; rem = t - 1048576; blk = rem >> 18; e = rem & 262143;
        src = W2; dst = wf + 1048576 + blk * 262144; kd = 1024; lg = 8; }
    else return;
    int k = e >> lg;
    int n = e & ((1 << lg) - 1);
    if (sect == 1) n = (n >> 2) * 8 + (n & 3);
    else if (sect == 2) n = (n >> 2) * 8 + 4 + (n & 3);
    float v = src[(size_t)blk * kd * (1 << lg) + e];
    int off = ((n >> 5) * (kd >> 4) + (k >> 4)) * 512 + (((k >> 3) & 1) * 32 + (n & 31)) * 8 + (k & 7);
    dst[off] = f2bf(v);
}

// LayerNorm (or plain convert) of fp32 [M,256] rows -> bf16 A-frag layout (KD=256).
__global__ __launch_bounds__(256) void ln_to_frag(
        const float* __restrict__ x, const float* __restrict__ g,
        const float* __restrict__ b, unsigned short* __restrict__ out,
        int apply_ln) {
    int wave = threadIdx.x >> 6, lane = threadIdx.x & 63;
    int m = blockIdx.x * 4 + wave;
    const float4 xv = reinterpret_cast<const float4*>(x + (size_t)m * DD)[lane];
    float vals[4] = {xv.x, xv.y, xv.z, xv.w};
    int k0 = lane * 4;
    if (apply_ln) {
        float s = vals[0] + vals[1] + vals[2] + vals[3];
        float sq = vals[0]*vals[0] + vals[1]*vals[1] + vals[2]*vals[2] + vals[3]*vals[3];
        for (int o = 32; o; o >>= 1) { s += __shfl_xor(s, o, 64); sq += __shfl_xor(sq, o, 64); }
        float mean = s * (1.0f / DD);
        float var = sq * (1.0f / DD) - mean * mean;
        float rs = rsqrtf(var + 1e-5f);
        #pragma unroll
        for (int c = 0; c < 4; ++c)
            vals[c] = (vals[c] - mean) * rs * g[k0 + c] + b[k0 + c];
    }
    int chunk = ((m >> 5) * (DD >> 4) + (k0 >> 4)) * 64 + ((k0 >> 3) & 1) * 32 + (m & 31);
    ushort4 o4 = make_ushort4(f2bf(vals[0]), f2bf(vals[1]), f2bf(vals[2]), f2bf(vals[3]));
    *reinterpret_cast<ushort4*>(out + (size_t)chunk * 8 + (k0 & 7)) = o4;
}

constexpr int GOUT_F32 = 0;
constexpr int GOUT_GELU_FRAG = 2;

// LDS-staged K-loop. wg = 4 waves = {2 m-halves} x {2 k-halves}; wg tile 128x64.
// BK=64 (4 k-groups/chunk; wave kh does kg = kh*2+{0,1}). Double-buffered 2x24KB.
// raw must be >= 49152 B. Leaves acc as this wave's k-partial; caller reduces.
template <int KG>
__device__ __forceinline__ void lds_gemm_core(
        const bf16x8* __restrict__ A, const bf16x8* __restrict__ B,
        int m0wg, int n0, char* raw, int wave, int lane, f32x16 acc[2][2]) {
    constexpr int C = KG / 4;
    const int mh = wave & 1, kh = wave >> 1;
    const int mrow = m0wg >> 5, nrow = n0 >> 5;
    // stage chunk c into buffer sel: 24 blocks of 1KB; wave w stages 6w..6w+5.
    auto stage = [&](int c, int sel) {
        char* base = raw + sel * 24576;
        #pragma unroll
        for (int s = 0; s < 6; ++s) {
            int b = wave * 6 + s;
            const bf16x8* src;
            if (b < 16)
                src = A + ((size_t)(mrow + (b >> 2)) * KG + c * 4 + (b & 3)) * 64 + lane;
            else
                src = B + ((size_t)(nrow + ((b - 16) >> 2)) * KG + c * 4 + ((b - 16) & 3)) * 64 + lane;
            gload_lds16(src, base + b * 1024);
        }
    };
    stage(0, 0);
    for (int c = 0; c < C; ++c) {
        __syncthreads();           // drains staging for chunk c; frees buffer (c+1)&1
        if (c + 1 < C) stage(c + 1, (c + 1) & 1);
        const char* base = raw + (c & 1) * 24576;
        #pragma unroll
        for (int t = 0; t < 2; ++t) {
            int kg = kh * 2 + t;
            bf16x8 av0 = *(const bf16x8*)(base + ((2 * mh + 0) * 4 + kg) * 1024 + lane * 16);
            bf16x8 av1 = *(const bf16x8*)(base + ((2 * mh + 1) * 4 + kg) * 1024 + lane * 16);
            bf16x8 bv0 = *(const bf16x8*)(base + 16384 + kg * 1024 + lane * 16);
            bf16x8 bv1 = *(const bf16x8*)(base + 16384 + (4 + kg) * 1024 + lane * 16);
            acc[0][0] = __builtin_amdgcn_mfma_f32_32x32x16_bf16(av0, bv0, acc[0][0], 0, 0, 0);
            acc[0][1] = __builtin_amdgcn_mfma_f32_32x32x16_bf16(av0, bv1, acc[0][1], 0, 0, 0);
            acc[1][0] = __builtin_amdgcn_mfma_f32_32x32x16_bf16(av1, bv0, acc[1][0], 0, 0, 0);
            acc[1][1] = __builtin_amdgcn_mfma_f32_32x32x16_bf16(av1, bv1, acc[1][1], 0, 0, 0);
        }
    }
    __syncthreads();               // all LDS reads done before reduce aliases staging
}

// C = A(frag) x B(frag), 256 thr. Split-K reduce in LDS, then epilogue.
template <int KD, int NOUT, int MODE, bool RESID, bool BIAS>
__global__ __launch_bounds__(256) void gemm_frag(
        const bf16x8* __restrict__ A, const bf16x8* __restrict__ B,
        void* __restrict__ outp, const float* __restrict__ resid,
        const float* __restrict__ bias, int out_kd) {
    constexpr int KG = KD / 16;
    __shared__ char raw[49152];
    int wave = threadIdx.x >> 6, lane = threadIdx.x & 63;
    int mh = wave & 1, kh = wave >> 1;
    int n0 = blockIdx.y * 64;
    f32x16 acc[2][2] = {};
    lds_gemm_core<KG>(A, B, blockIdx.x * 128, n0, raw, wave, lane, acc);
    int col = lane & 31, rq = (lane >> 5) * 4;
    float* red = (float*)raw;
    if (kh == 1) {
        #pragma unroll
        for (int i = 0; i < 2; ++i)
        #pragma unroll
        for (int j = 0; j < 2; ++j)
        #pragma unroll
        for (int r = 0; r < 16; ++r) {
            int row = (r & 3) + 8 * (r >> 2) + rq + i * 32;
            red[mh * 4096 + row * 64 + j * 32 + col] = acc[i][j][r];
        }
    }
    __syncthreads();
    if (kh == 1) return;
    #pragma unroll
    for (int i = 0; i < 2; ++i)
    #pragma unroll
    for (int j = 0; j < 2; ++j)
    #pragma unroll
    for (int r = 0; r < 16; ++r) {
        int row = (r & 3) + 8 * (r >> 2) + rq + i * 32;
        acc[i][j][r] += red[mh * 4096 + row * 64 + j * 32 + col];
    }
    int m0 = blockIdx.x * 128 + mh * 64;
    if constexpr (MODE == GOUT_F32) {
        #pragma unroll
        for (int i = 0; i < 2; ++i)
        #pragma unroll
        for (int j = 0; j < 2; ++j) {
            #pragma unroll
            for (int r = 0; r < 16; ++r) {
                int row = (r & 3) + 8 * (r >> 2) + rq;
                int m = m0 + i * 32 + row;
                int n = n0 + j * 32 + col;
                float v = acc[i][j][r];
                if (BIAS) v += bias[n];
                if (RESID) v += resid[(size_t)m * NOUT + n];
                ((float*)outp)[(size_t)m * NOUT + n] = v;
            }
        }
    } else {
        // GELU -> bf16 A-frag. Wave-private pad-33 tile above the reduce region.
        float* wlds = (float*)(raw + 32768) + mh * 1056;
        for (int i = 0; i < 2; ++i)
        for (int j = 0; j < 2; ++j) {
            #pragma unroll
            for (int r = 0; r < 16; ++r) {
                int row = (r & 3) + 8 * (r >> 2) + rq;
                int n = n0 + j * 32 + col;
                float v = acc[i][j][r] + bias[n];
                float arg = v * (1.5957691216f + 0.0713548163f * v * v);
                v = v * __frcp_rn(1.0f + __expf(-arg));
                wlds[row * 33 + col] = v;
            }
            #pragma unroll
            for (int it = 0; it < 2; ++it) {
                int task = lane + it * 64;
                int row = task >> 2, cc = task & 3;
                int m = m0 + i * 32 + row;
                int k = n0 + j * 32 + cc * 8;
                float* p = &wlds[row * 33 + cc * 8];
                unsigned short us[8];
                #pragma unroll
                for (int e = 0; e < 8; ++e) us[e] = f2bf(p[e]);
                int chunk = ((m >> 5) * (out_kd >> 4) + (k >> 4)) * 64 + ((k >> 3) & 1) * 32 + (m & 31);
                reinterpret_cast<uint4*>(outp)[chunk] = *reinterpret_cast<uint4*>(us);
            }
        }
    }
}

// Fused Q + KV projections (LDS-staged). grid.y 0..3 -> Q (bf16), 4..11 -> KV (fp8).
__global__ __launch_bounds__(256) void gemm_qkv(
        const bf16x8* __restrict__ Aq, const bf16x8* __restrict__ Akv,
        const bf16x8* __restrict__ Bq, const bf16x8* __restrict__ Bkv,
        unsigned short* __restrict__ qout, unsigned char* __restrict__ kvout) {
    __shared__ char raw[49152];
    int wave = threadIdx.x >> 6, lane = threadIdx.x & 63;
    int mh = wave & 1, kh = wave >> 1;
    int y = blockIdx.y;
    bool isQ = y < 4;
    const bf16x8* A = isQ ? Aq : Akv;
    const bf16x8* B = isQ ? Bq : Bkv;
    int n0 = (isQ ? y : y - 4) * 64;
    f32x16 acc[2][2] = {};
    lds_gemm_core<16>(A, B, blockIdx.x * 128, n0, raw, wave, lane, acc);
    int col = lane & 31, rq = (lane >> 5) * 4;
    float* red = (float*)raw;
    if (kh == 1) {
        #pragma unroll
        for (int i = 0; i < 2; ++i)
        #pragma unroll
        for (int j = 0; j < 2; ++j)
        #pragma unroll
        for (int r = 0; r < 16; ++r) {
            int row = (r & 3) + 8 * (r >> 2) + rq + i * 32;
            red[mh * 4096 + row * 64 + j * 32 + col] = acc[i][j][r];
        }
    }
    __syncthreads();
    if (kh == 1) return;
    int m0 = blockIdx.x * 128 + mh * 64;
    #pragma unroll
    for (int i = 0; i < 2; ++i)
    #pragma unroll
    for (int j = 0; j < 2; ++j)
    #pragma unroll
    for (int r = 0; r < 16; ++r) {
        int row = (r & 3) + 8 * (r >> 2) + rq;
        int m = m0 + i * 32 + row;
        int n = n0 + j * 32 + col;
        float v = acc[i][j][r] + red[mh * 4096 + (row + i * 32) * 64 + j * 32 + col];
        if (isQ) qout[(size_t)m * 256 + n] = f2bf(v);
        else kvout[(size_t)m * 512 + n] =
            (unsigned char)(__builtin_amdgcn_cvt_pk_fp8_f32(v, v, 0, false) & 0xff);
    }
}

// One wave per point. lane = h*16+s; dims d0 = h*64+s*4.
// Distributed scores; pe handled algebraically. kv rows: 512 B fp8.
__global__ __launch_bounds__(256) void attn_kernel(
        const unsigned short* __restrict__ q, const unsigned char* __restrict__ kv,
        const float* __restrict__ coord, const float* __restrict__ ctx_coord,
        const int* __restrict__ knn,
        const float* __restrict__ pe_w, const float* __restrict__ pe_b,
        unsigned short* __restrict__ out_frag) {
    int wave = threadIdx.x >> 6, lane = threadIdx.x & 63;
    int m = blockIdx.x * 4 + wave;
    int s = lane & 15;
    int d0 = (lane >> 4) * 64 + s * 4;

    ushort4 qv4 = *reinterpret_cast<const ushort4*>(q + (size_t)m * DD + d0);
    float qx = bf2f(qv4.x), qy = bf2f(qv4.y), qz = bf2f(qv4.z), qw = bf2f(qv4.w);
    float4 pw0 = *reinterpret_cast<const float4*>(pe_w + d0);
    float4 pw1 = *reinterpret_cast<const float4*>(pe_w + DD + d0);
    float4 pw2 = *reinterpret_cast<const float4*>(pe_w + 2 * DD + d0);
    float4 pbv = *reinterpret_cast<const float4*>(pe_b + d0);

    float cx = coord[m * 3], cy = coord[m * 3 + 1], cz = coord[m * 3 + 2];
    int myidx = knn[(size_t)m * KK + s];
    int icm = myidx < 0 ? 0 : myidx;
    float rx = cx - ctx_coord[icm * 3];
    float ry = cy - ctx_coord[icm * 3 + 1];
    float rz = cz - ctx_coord[icm * 3 + 2];

    float t0 = qx * pw0.x + qy * pw0.y + qz * pw0.z + qw * pw0.w;
    float t1 = qx * pw1.x + qy * pw1.y + qz * pw1.z + qw * pw1.w;
    float t2 = qx * pw2.x + qy * pw2.y + qz * pw2.z + qw * pw2.w;
    float t3 = qx * pbv.x + qy * pbv.y + qz * pbv.z + qw * pbv.w;
    #pragma unroll
    for (int o = 1; o < 16; o <<= 1) {
        t0 += __shfl_xor(t0, o, 64);
        t1 += __shfl_xor(t1, o, 64);
        t2 += __shfl_xor(t2, o, 64);
        t3 += __shfl_xor(t3, o, 64);
    }

    float sc_own = 0.0f;
    unsigned vpk[KK];
    #pragma unroll
    for (int j = 0; j < KK; ++j) {
        int ij = __shfl(myidx, j, 64);
        int ic = ij < 0 ? 0 : ij;
        uint2 kvv = *reinterpret_cast<const uint2*>(kv + (size_t)ic * 512 + (d0 >> 2) * 8);
        vpk[j] = kvv.y;
        f32x2 k01 = __builtin_amdgcn_cvt_pk_f32_fp8(kvv.x, false);
        f32x2 k23 = __builtin_amdgcn_cvt_pk_f32_fp8(kvv.x, true);
        float p = qx * k01.x + qy * k01.y + qz * k23.x + qw * k23.y;
        p += __shfl_xor(p, 1, 64);
        p += __shfl_xor(p, 2, 64);
        p += __shfl_xor(p, 4, 64);
        p += __shfl_xor(p, 8, 64);
        sc_own = (j == s) ? p : sc_own;
    }
    float corr = rx * t0 + ry * t1 + rz * t2 + t3;
    sc_own = (myidx >= 0) ? (sc_own + corr) * 0.125f : -1e9f;

    float mx = sc_own;
    mx = fmaxf(mx, __shfl_xor(mx, 1, 64));
    mx = fmaxf(mx, __shfl_xor(mx, 2, 64));
    mx = fmaxf(mx, __shfl_xor(mx, 4, 64));
    mx = fmaxf(mx, __shfl_xor(mx, 8, 64));
    float e = __expf(sc_own - mx);
    float sum = e;
    sum += __shfl_xor(sum, 1, 64);
    sum += __shfl_xor(sum, 2, 64);
    sum += __shfl_xor(sum, 4, 64);
    sum += __shfl_xor(sum, 8, 64);
    float w_own = e * __frcp_rn(sum);

    float wrx = w_own * rx, wry = w_own * ry, wrz = w_own * rz;
    #pragma unroll
    for (int o = 1; o < 16; o <<= 1) {
        wrx += __shfl_xor(wrx, o, 64);
        wry += __shfl_xor(wry, o, 64);
        wrz += __shfl_xor(wrz, o, 64);
    }

    int gbase = lane & 48;
    float ax = 0.f, ay = 0.f, az = 0.f, aw = 0.f;
    #pragma unroll
    for (int j = 0; j < KK; ++j) {
        float wj = __shfl(w_own, gbase + j, 64);
        f32x2 v01 = __builtin_amdgcn_cvt_pk_f32_fp8(vpk[j], false);
        f32x2 v23 = __builtin_amdgcn_cvt_pk_f32_fp8(vpk[j], true);
        ax += wj * v01.x;
        ay += wj * v01.y;
        az += wj * v23.x;
        aw += wj * v23.y;
    }
    ax += wrx * pw0.x + wry * pw1.x + wrz * pw2.x + pbv.x;
    ay += wrx * pw0.y + wry * pw1.y + wrz * pw2.y + pbv.y;
    az += wrx * pw0.z + wry * pw1.z + wrz * pw2.z + pbv.z;
    aw += wrx * pw0.w + wry * pw1.w + wrz * pw2.w + pbv.w;

    ushort4 o4 = make_ushort4(f2bf(ax), f2bf(ay), f2bf(az), f2bf(aw));
    int chunk = ((m >> 5) * (DD >> 4) + (d0 >> 4)) * 64 + ((d0 >> 3) & 1) * 32 + (m & 31);
    *reinterpret_cast<ushort4*>(out_frag + (size_t)chunk * 8 + (d0 & 7)) = o4;
}

extern "C" void kernel_launch(void* const* d_in, const int* in_sizes, int n_in,
                              void* d_out, int out_size, void* d_ws, size_t ws_size,
                              hipStream_t stream) {
    const float* feat_a = (const float*)d_in[0];
    const float* coord_a = (const float*)d_in[1];
    const float* feat_b = (const float*)d_in[2];
    const float* coord_b = (const float*)d_in[3];
    const float* Wq = (const float*)d_in[4];
    const float* Wk = (const float*)d_in[5];
    const float* Wv = (const float*)d_in[6];
    const float* Wo = (const float*)d_in[7];
    const float* ln1_g = (const float*)d_in[8];
    const float* ln1_b = (const float*)d_in[9];
    const float* pe_w = (const float*)d_in[10];
    const float* pe_b = (const float*)d_in[11];
    const float* W1 = (const float*)d_in[12];
    const float* b1 = (const float*)d_in[13];
    const float* W2 = (const float*)d_in[14];
    const float* b2 = (const float*)d_in[15];
    const float* ln2_g = (const float*)d_in[16];
    const float* ln2_b = (const float*)d_in[17];
    const int* knn_a2a = (const int*)d_in[18];
    const int* knn_a2b = (const int*)d_in[19];

    char* ws = (char*)d_ws;
    unsigned short* wfrag = (unsigned short*)ws;                  // 3 MB (4 MB region)
    float* xmid = (float*)(ws + (4ull << 20));                    // 16 MB
    float* xout0 = (float*)(ws + (20ull << 20));                  // 16 MB
    unsigned short* qbuf = (unsigned short*)(ws + (36ull << 20)); // 8 MB
    unsigned char* kvbuf = (unsigned char*)(ws + (52ull << 20));  // 8 MB (fp8)
    unsigned short* xnf = (unsigned short*)(ws + (68ull << 20));  // 8 MB
    unsigned short* ctxf = (unsigned short*)(ws + (76ull << 20)); // 8 MB
    unsigned short* attnf = (unsigned short*)(ws + (84ull << 20));// 8 MB -> 92 MB
    unsigned short* geluf = (unsigned short*)(ws + (36ull << 20));// 32 MB, overlays q/kv (dead by FFN)

    const unsigned short* WQF = wfrag;
    const unsigned short* KVF = wfrag + 131072;
    const unsigned short* WOF = wfrag + 393216;
    const unsigned short* W1F = wfrag + 524288;
    const unsigned short* W2F = wfrag + 1048576;

    prep_weights<<<(1572864 + 255) / 256, 256, 0, stream>>>(Wq, Wk, Wv, Wo, W1, W2, wfrag);

    for (int blk = 0; blk < 2; ++blk) {
        const float* x_in = blk ? xout0 : feat_a;
        const float* ctx = blk ? feat_b : feat_a;
        const float* ccrd = blk ? coord_b : coord_a;
        const int* knn = blk ? knn_a2b : knn_a2a;
        float* x_out_final = blk ? (float*)d_out : xout0;

        ln_to_frag<<<MM / 4, 256, 0, stream>>>(ctx, nullptr, nullptr, ctxf, 0);
        ln_to_frag<<<MM / 4, 256, 0, stream>>>(x_in, ln1_g + blk * DD, ln1_b + blk * DD, xnf, 1);

        gemm_qkv<<<dim3(MM / 128, 12), 256, 0, stream>>>(
            (const bf16x8*)xnf, (const bf16x8*)ctxf,
            (const bf16x8*)(WQF + blk * 65536), (const bf16x8*)(KVF + blk * 131072),
            qbuf, kvbuf);

        attn_kernel<<<MM / 4, 256, 0, stream>>>(qbuf, kvbuf, coord_a, ccrd, knn,
                                                pe_w + blk * 3 * DD, pe_b + blk * DD, attnf);

        gemm_frag<256, 256, GOUT_F32, true, false><<<dim3(MM / 128, 4), 256, 0, stream>>>(
            (const bf16x8*)attnf, (const bf16x8*)(WOF + blk * 65536), xmid, x_in, nullptr, 0);

        ln_to_frag<<<MM / 4, 256, 0, stream>>>(xmid, ln2_g + blk * DD, ln2_b + blk * DD, xnf, 1);

        gemm_frag<256, 1024, GOUT_GELU_FRAG, false, true><<<dim3(MM / 128, 16), 256, 0, stream>>>(
            (const bf16x8*)xnf, (const bf16x8*)(W1F + blk * 262144), geluf, nullptr,
            b1 + blk * DFF_, 1024);

        gemm_frag<1024, 256, GOUT_F32, true, true><<<dim3(MM / 128, 4), 256, 0, stream>>>(
            (const bf16x8*)geluf, (const bf16x8*)(W2F + blk * 262144), x_out_final, xmid,
            b2 + blk * DD, 0);
    }
}

// Round 10
// 349.692 us; speedup vs baseline: 1.0645x; 1.0645x over previous
//
#include <hip/hip_runtime.h>
#include <hip/hip_bf16.h>
#include <stdint.h>

#define MM 16384
#define DD 256
#define HH 4
#define KK 16
#define DFF_ 1024

typedef __attribute__((ext_vector_type(8))) short bf16x8;
typedef __attribute__((ext_vector_type(16))) float f32x16;
typedef __attribute__((ext_vector_type(2))) float f32x2;

__device__ __forceinline__ unsigned short f2bf(float f) {
    unsigned u = __builtin_bit_cast(unsigned, f);
    unsigned r = u + 0x7fffu + ((u >> 16) & 1u);
    return (unsigned short)(r >> 16);
}
__device__ __forceinline__ float bf2f(unsigned short h) {
    unsigned u = ((unsigned)h) << 16;
    return __builtin_bit_cast(float, u);
}

// ---------------------------------------------------------------------------
// Fragment layouts (bf16, 16B chunks of 8 elems):
// A-frag (row m, k):  chunk = ((m>>5)*(KD/16) + (k>>4))*64 + ((k>>3)&1)*32 + (m&31), elem = k&7
// B-frag (col n, k):  same with n.
// v_mfma_f32_32x32x16_bf16 C/D: col=lane&31, row=(reg&3)+8*(reg>>2)+4*(lane>>5)
// kv buffer: fp8 e4m3 rows of 512 B, groups of 8 B = [K4 | V4].
// NOTE (R4): 64x128 wave tiles (acc[2][4]) spill -> keep 64x64 (acc[2][2]).
// NOTE (R5): gelu: sigmoid form + pad-33 LDS + no barriers.
// NOTE (R6): full-row LN fusion (1 wg/CU) regressed; reverted.
// NOTE (R9): m97-style LDS staging REGRESSED here (C=4 chunks, 8 MFMA/barrier,
//   48KB LDS -> barrier-drain dominated, 64us gelu). Short-K GEMMs want direct
//   frag loads. This round: square 128x128 wg tiles (4 waves, 2m x 2n, serial K)
//   -> halves L2 operand traffic, no split-K barriers, same 64-reg acc shape.
// ---------------------------------------------------------------------------

// wfrag layout (shorts): WQF@0 (blk stride 65536), KVF@131072 (131072),
//   WOF@393216 (65536), W1F@524288 (262144), W2F@1048576 (262144)
__global__ __launch_bounds__(256) void prep_weights(
        const float* __restrict__ Wq, const float* __restrict__ Wk,
        const float* __restrict__ Wv, const float* __restrict__ Wo,
        const float* __restrict__ W1, const float* __restrict__ W2,
        unsigned short* __restrict__ wf) {
    int t = blockIdx.x * blockDim.x + threadIdx.x;
    const float* src; unsigned short* dst;
    int kd, lg, rem, blk, e, sect;
    if (t < 131072) { sect = 0; rem = t; blk = rem >> 16; e = rem & 65535;
        src = Wq; dst = wf + blk * 65536; kd = 256; lg = 8; }
    else if (t < 262144) { sect = 1; rem = t - 131072; blk = rem >> 16; e = rem & 65535;
        src = Wk; dst = wf + 131072 + blk * 131072; kd = 256; lg = 8; }
    else if (t < 393216) { sect = 2; rem = t - 262144; blk = rem >> 16; e = rem & 65535;
        src = Wv; dst = wf + 131072 + blk * 131072; kd = 256; lg = 8; }
    else if (t < 524288) { sect = 0; rem = t - 393216; blk = rem >> 16; e = rem & 65535;
        src = Wo; dst = wf + 393216 + blk * 65536; kd = 256; lg = 8; }
    else if (t < 1048576) { sect = 0; rem = t - 524288; blk = rem >> 18; e = rem & 262143;
        src = W1; dst = wf + 524288 + blk * 262144; kd = 256; lg = 10; }
    else if (t < 1572864) { sect = 0; rem = t - 1048576; blk = rem >> 18; e = rem & 262143;
        src = W2; dst = wf + 1048576 + blk * 262144; kd = 1024; lg = 8; }
    else return;
    int k = e >> lg;
    int n = e & ((1 << lg) - 1);
    if (sect == 1) n = (n >> 2) * 8 + (n & 3);
    else if (sect == 2) n = (n >> 2) * 8 + 4 + (n & 3);
    float v = src[(size_t)blk * kd * (1 << lg) + e];
    int off = ((n >> 5) * (kd >> 4) + (k >> 4)) * 512 + (((k >> 3) & 1) * 32 + (n & 31)) * 8 + (k & 7);
    dst[off] = f2bf(v);
}

// LayerNorm (or plain convert) of fp32 [M,256] rows -> bf16 A-frag layout (KD=256).
__global__ __launch_bounds__(256) void ln_to_frag(
        const float* __restrict__ x, const float* __restrict__ g,
        const float* __restrict__ b, unsigned short* __restrict__ out,
        int apply_ln) {
    int wave = threadIdx.x >> 6, lane = threadIdx.x & 63;
    int m = blockIdx.x * 4 + wave;
    const float4 xv = reinterpret_cast<const float4*>(x + (size_t)m * DD)[lane];
    float vals[4] = {xv.x, xv.y, xv.z, xv.w};
    int k0 = lane * 4;
    if (apply_ln) {
        float s = vals[0] + vals[1] + vals[2] + vals[3];
        float sq = vals[0]*vals[0] + vals[1]*vals[1] + vals[2]*vals[2] + vals[3]*vals[3];
        for (int o = 32; o; o >>= 1) { s += __shfl_xor(s, o, 64); sq += __shfl_xor(sq, o, 64); }
        float mean = s * (1.0f / DD);
        float var = sq * (1.0f / DD) - mean * mean;
        float rs = rsqrtf(var + 1e-5f);
        #pragma unroll
        for (int c = 0; c < 4; ++c)
            vals[c] = (vals[c] - mean) * rs * g[k0 + c] + b[k0 + c];
    }
    int chunk = ((m >> 5) * (DD >> 4) + (k0 >> 4)) * 64 + ((k0 >> 3) & 1) * 32 + (m & 31);
    ushort4 o4 = make_ushort4(f2bf(vals[0]), f2bf(vals[1]), f2bf(vals[2]), f2bf(vals[3]));
    *reinterpret_cast<ushort4*>(out + (size_t)chunk * 8 + (k0 & 7)) = o4;
}

constexpr int GOUT_F32 = 0;
constexpr int GOUT_GELU_FRAG = 2;

template <int KG>
__device__ __forceinline__ void compute_tile(
        const bf16x8* __restrict__ a0, const bf16x8* __restrict__ a1,
        const bf16x8* __restrict__ b0, const bf16x8* __restrict__ b1,
        f32x16 acc[2][2]) {
    #pragma unroll 4
    for (int g = 0; g < KG; ++g) {
        bf16x8 av0 = a0[g * 64];
        bf16x8 av1 = a1[g * 64];
        bf16x8 bv0 = b0[g * 64];
        bf16x8 bv1 = b1[g * 64];
        acc[0][0] = __builtin_amdgcn_mfma_f32_32x32x16_bf16(av0, bv0, acc[0][0], 0, 0, 0);
        acc[0][1] = __builtin_amdgcn_mfma_f32_32x32x16_bf16(av0, bv1, acc[0][1], 0, 0, 0);
        acc[1][0] = __builtin_amdgcn_mfma_f32_32x32x16_bf16(av1, bv0, acc[1][0], 0, 0, 0);
        acc[1][1] = __builtin_amdgcn_mfma_f32_32x32x16_bf16(av1, bv1, acc[1][1], 0, 0, 0);
    }
}

// C = A(frag) x B(frag). wg = 128x128 tile, 4 waves = 2m x 2n, each 64x64,
// serial K (no split-K, no K-loop barriers).
template <int KD, int NOUT, int MODE, bool RESID, bool BIAS>
__global__ __launch_bounds__(256) void gemm_frag(
        const bf16x8* __restrict__ A, const bf16x8* __restrict__ B,
        void* __restrict__ outp, const float* __restrict__ resid,
        const float* __restrict__ bias, int out_kd) {
    constexpr int KG = KD / 16;
    __shared__ float lds[MODE == GOUT_GELU_FRAG ? 4 * 1056 : 4];
    int wave = threadIdx.x >> 6, lane = threadIdx.x & 63;
    int wm = wave & 1, wn = wave >> 1;
    int m0 = blockIdx.x * 128 + wm * 64;
    int n0 = blockIdx.y * 128 + wn * 64;
    const bf16x8* a0 = A + ((size_t)(m0 >> 5) * KG) * 64 + lane;
    const bf16x8* a1 = a0 + (size_t)KG * 64;
    const bf16x8* b0 = B + ((size_t)(n0 >> 5) * KG) * 64 + lane;
    const bf16x8* b1 = b0 + (size_t)KG * 64;
    f32x16 acc[2][2] = {};
    compute_tile<KG>(a0, a1, b0, b1, acc);
    int col = lane & 31, rq = (lane >> 5) * 4;
    if constexpr (MODE == GOUT_F32) {
        #pragma unroll
        for (int i = 0; i < 2; ++i)
        #pragma unroll
        for (int j = 0; j < 2; ++j) {
            #pragma unroll
            for (int r = 0; r < 16; ++r) {
                int row = (r & 3) + 8 * (r >> 2) + rq;
                int m = m0 + i * 32 + row;
                int n = n0 + j * 32 + col;
                float v = acc[i][j][r];
                if (BIAS) v += bias[n];
                if (RESID) v += resid[(size_t)m * NOUT + n];
                ((float*)outp)[(size_t)m * NOUT + n] = v;
            }
        }
    } else {
        // GELU -> bf16 A-frag. Wave-private pad-33 tile, no barriers.
        float* wlds = &lds[wave * 1056];
        for (int i = 0; i < 2; ++i)
        for (int j = 0; j < 2; ++j) {
            #pragma unroll
            for (int r = 0; r < 16; ++r) {
                int row = (r & 3) + 8 * (r >> 2) + rq;
                int n = n0 + j * 32 + col;
                float v = acc[i][j][r] + bias[n];
                float arg = v * (1.5957691216f + 0.0713548163f * v * v);
                v = v * __frcp_rn(1.0f + __expf(-arg));
                wlds[row * 33 + col] = v;
            }
            #pragma unroll
            for (int it = 0; it < 2; ++it) {
                int task = lane + it * 64;
                int row = task >> 2, cc = task & 3;
                int m = m0 + i * 32 + row;
                int k = n0 + j * 32 + cc * 8;
                float* p = &wlds[row * 33 + cc * 8];
                unsigned short us[8];
                #pragma unroll
                for (int e = 0; e < 8; ++e) us[e] = f2bf(p[e]);
                int chunk = ((m >> 5) * (out_kd >> 4) + (k >> 4)) * 64 + ((k >> 3) & 1) * 32 + (m & 31);
                reinterpret_cast<uint4*>(outp)[chunk] = *reinterpret_cast<uint4*>(us);
            }
        }
    }
}

// Fused Q + KV projections, 128x128 wg tiles, serial K.
// grid.y 0..1 -> Q (bf16 out, stride 256); 2..5 -> KV (fp8 out, stride 512).
__global__ __launch_bounds__(256) void gemm_qkv(
        const bf16x8* __restrict__ Aq, const bf16x8* __restrict__ Akv,
        const bf16x8* __restrict__ Bq, const bf16x8* __restrict__ Bkv,
        unsigned short* __restrict__ qout, unsigned char* __restrict__ kvout) {
    constexpr int KG = 16;
    int wave = threadIdx.x >> 6, lane = threadIdx.x & 63;
    int wm = wave & 1, wn = wave >> 1;
    int y = blockIdx.y;
    bool isQ = y < 2;
    const bf16x8* A = isQ ? Aq : Akv;
    const bf16x8* B = isQ ? Bq : Bkv;
    int n0 = (isQ ? y : y - 2) * 128 + wn * 64;
    int m0 = blockIdx.x * 128 + wm * 64;
    const bf16x8* a0 = A + ((size_t)(m0 >> 5) * KG) * 64 + lane;
    const bf16x8* a1 = a0 + (size_t)KG * 64;
    const bf16x8* b0 = B + ((size_t)(n0 >> 5) * KG) * 64 + lane;
    const bf16x8* b1 = b0 + (size_t)KG * 64;
    f32x16 acc[2][2] = {};
    compute_tile<KG>(a0, a1, b0, b1, acc);
    int col = lane & 31, rq = (lane >> 5) * 4;
    #pragma unroll
    for (int i = 0; i < 2; ++i)
    #pragma unroll
    for (int j = 0; j < 2; ++j)
    #pragma unroll
    for (int r = 0; r < 16; ++r) {
        int row = (r & 3) + 8 * (r >> 2) + rq;
        int m = m0 + i * 32 + row;
        int n = n0 + j * 32 + col;
        float v = acc[i][j][r];
        if (isQ) qout[(size_t)m * 256 + n] = f2bf(v);
        else kvout[(size_t)m * 512 + n] =
            (unsigned char)(__builtin_amdgcn_cvt_pk_fp8_f32(v, v, 0, false) & 0xff);
    }
}

// One wave per point. lane = h*16+s; dims d0 = h*64+s*4.
// Distributed scores; pe handled algebraically. kv rows: 512 B fp8.
__global__ __launch_bounds__(256) void attn_kernel(
        const unsigned short* __restrict__ q, const unsigned char* __restrict__ kv,
        const float* __restrict__ coord, const float* __restrict__ ctx_coord,
        const int* __restrict__ knn,
        const float* __restrict__ pe_w, const float* __restrict__ pe_b,
        unsigned short* __restrict__ out_frag) {
    int wave = threadIdx.x >> 6, lane = threadIdx.x & 63;
    int m = blockIdx.x * 4 + wave;
    int s = lane & 15;
    int d0 = (lane >> 4) * 64 + s * 4;

    ushort4 qv4 = *reinterpret_cast<const ushort4*>(q + (size_t)m * DD + d0);
    float qx = bf2f(qv4.x), qy = bf2f(qv4.y), qz = bf2f(qv4.z), qw = bf2f(qv4.w);
    float4 pw0 = *reinterpret_cast<const float4*>(pe_w + d0);
    float4 pw1 = *reinterpret_cast<const float4*>(pe_w + DD + d0);
    float4 pw2 = *reinterpret_cast<const float4*>(pe_w + 2 * DD + d0);
    float4 pbv = *reinterpret_cast<const float4*>(pe_b + d0);

    float cx = coord[m * 3], cy = coord[m * 3 + 1], cz = coord[m * 3 + 2];
    int myidx = knn[(size_t)m * KK + s];
    int icm = myidx < 0 ? 0 : myidx;
    float rx = cx - ctx_coord[icm * 3];
    float ry = cy - ctx_coord[icm * 3 + 1];
    float rz = cz - ctx_coord[icm * 3 + 2];

    float t0 = qx * pw0.x + qy * pw0.y + qz * pw0.z + qw * pw0.w;
    float t1 = qx * pw1.x + qy * pw1.y + qz * pw1.z + qw * pw1.w;
    float t2 = qx * pw2.x + qy * pw2.y + qz * pw2.z + qw * pw2.w;
    float t3 = qx * pbv.x + qy * pbv.y + qz * pbv.z + qw * pbv.w;
    #pragma unroll
    for (int o = 1; o < 16; o <<= 1) {
        t0 += __shfl_xor(t0, o, 64);
        t1 += __shfl_xor(t1, o, 64);
        t2 += __shfl_xor(t2, o, 64);
        t3 += __shfl_xor(t3, o, 64);
    }

    float sc_own = 0.0f;
    unsigned vpk[KK];
    #pragma unroll
    for (int j = 0; j < KK; ++j) {
        int ij = __shfl(myidx, j, 64);
        int ic = ij < 0 ? 0 : ij;
        uint2 kvv = *reinterpret_cast<const uint2*>(kv + (size_t)ic * 512 + (d0 >> 2) * 8);
        vpk[j] = kvv.y;
        f32x2 k01 = __builtin_amdgcn_cvt_pk_f32_fp8(kvv.x, false);
        f32x2 k23 = __builtin_amdgcn_cvt_pk_f32_fp8(kvv.x, true);
        float p = qx * k01.x + qy * k01.y + qz * k23.x + qw * k23.y;
        p += __shfl_xor(p, 1, 64);
        p += __shfl_xor(p, 2, 64);
        p += __shfl_xor(p, 4, 64);
        p += __shfl_xor(p, 8, 64);
        sc_own = (j == s) ? p : sc_own;
    }
    float corr = rx * t0 + ry * t1 + rz * t2 + t3;
    sc_own = (myidx >= 0) ? (sc_own + corr) * 0.125f : -1e9f;

    float mx = sc_own;
    mx = fmaxf(mx, __shfl_xor(mx, 1, 64));
    mx = fmaxf(mx, __shfl_xor(mx, 2, 64));
    mx = fmaxf(mx, __shfl_xor(mx, 4, 64));
    mx = fmaxf(mx, __shfl_xor(mx, 8, 64));
    float e = __expf(sc_own - mx);
    float sum = e;
    sum += __shfl_xor(sum, 1, 64);
    sum += __shfl_xor(sum, 2, 64);
    sum += __shfl_xor(sum, 4, 64);
    sum += __shfl_xor(sum, 8, 64);
    float w_own = e * __frcp_rn(sum);

    float wrx = w_own * rx, wry = w_own * ry, wrz = w_own * rz;
    #pragma unroll
    for (int o = 1; o < 16; o <<= 1) {
        wrx += __shfl_xor(wrx, o, 64);
        wry += __shfl_xor(wry, o, 64);
        wrz += __shfl_xor(wrz, o, 64);
    }

    int gbase = lane & 48;
    float ax = 0.f, ay = 0.f, az = 0.f, aw = 0.f;
    #pragma unroll
    for (int j = 0; j < KK; ++j) {
        float wj = __shfl(w_own, gbase + j, 64);
        f32x2 v01 = __builtin_amdgcn_cvt_pk_f32_fp8(vpk[j], false);
        f32x2 v23 = __builtin_amdgcn_cvt_pk_f32_fp8(vpk[j], true);
        ax += wj * v01.x;
        ay += wj * v01.y;
        az += wj * v23.x;
        aw += wj * v23.y;
    }
    ax += wrx * pw0.x + wry * pw1.x + wrz * pw2.x + pbv.x;
    ay += wrx * pw0.y + wry * pw1.y + wrz * pw2.y + pbv.y;
    az += wrx * pw0.z + wry * pw1.z + wrz * pw2.z + pbv.z;
    aw += wrx * pw0.w + wry * pw1.w + wrz * pw2.w + pbv.w;

    ushort4 o4 = make_ushort4(f2bf(ax), f2bf(ay), f2bf(az), f2bf(aw));
    int chunk = ((m >> 5) * (DD >> 4) + (d0 >> 4)) * 64 + ((d0 >> 3) & 1) * 32 + (m & 31);
    *reinterpret_cast<ushort4*>(out_frag + (size_t)chunk * 8 + (d0 & 7)) = o4;
}

extern "C" void kernel_launch(void* const* d_in, const int* in_sizes, int n_in,
                              void* d_out, int out_size, void* d_ws, size_t ws_size,
                              hipStream_t stream) {
    const float* feat_a = (const float*)d_in[0];
    const float* coord_a = (const float*)d_in[1];
    const float* feat_b = (const float*)d_in[2];
    const float* coord_b = (const float*)d_in[3];
    const float* Wq = (const float*)d_in[4];
    const float* Wk = (const float*)d_in[5];
    const float* Wv = (const float*)d_in[6];
    const float* Wo = (const float*)d_in[7];
    const float* ln1_g = (const float*)d_in[8];
    const float* ln1_b = (const float*)d_in[9];
    const float* pe_w = (const float*)d_in[10];
    const float* pe_b = (const float*)d_in[11];
    const float* W1 = (const float*)d_in[12];
    const float* b1 = (const float*)d_in[13];
    const float* W2 = (const float*)d_in[14];
    const float* b2 = (const float*)d_in[15];
    const float* ln2_g = (const float*)d_in[16];
    const float* ln2_b = (const float*)d_in[17];
    const int* knn_a2a = (const int*)d_in[18];
    const int* knn_a2b = (const int*)d_in[19];

    char* ws = (char*)d_ws;
    unsigned short* wfrag = (unsigned short*)ws;                  // 3 MB (4 MB region)
    float* xmid = (float*)(ws + (4ull << 20));                    // 16 MB
    float* xout0 = (float*)(ws + (20ull << 20));                  // 16 MB
    unsigned short* qbuf = (unsigned short*)(ws + (36ull << 20)); // 8 MB
    unsigned char* kvbuf = (unsigned char*)(ws + (52ull << 20));  // 8 MB (fp8)
    unsigned short* xnf = (unsigned short*)(ws + (68ull << 20));  // 8 MB
    unsigned short* ctxf = (unsigned short*)(ws + (76ull << 20)); // 8 MB
    unsigned short* attnf = (unsigned short*)(ws + (84ull << 20));// 8 MB -> 92 MB
    unsigned short* geluf = (unsigned short*)(ws + (36ull << 20));// 32 MB, overlays q/kv (dead by FFN)

    const unsigned short* WQF = wfrag;
    const unsigned short* KVF = wfrag + 131072;
    const unsigned short* WOF = wfrag + 393216;
    const unsigned short* W1F = wfrag + 524288;
    const unsigned short* W2F = wfrag + 1048576;

    prep_weights<<<(1572864 + 255) / 256, 256, 0, stream>>>(Wq, Wk, Wv, Wo, W1, W2, wfrag);

    for (int blk = 0; blk < 2; ++blk) {
        const float* x_in = blk ? xout0 : feat_a;
        const float* ctx = blk ? feat_b : feat_a;
        const float* ccrd = blk ? coord_b : coord_a;
        const int* knn = blk ? knn_a2b : knn_a2a;
        float* x_out_final = blk ? (float*)d_out : xout0;

        ln_to_frag<<<MM / 4, 256, 0, stream>>>(ctx, nullptr, nullptr, ctxf, 0);
        ln_to_frag<<<MM / 4, 256, 0, stream>>>(x_in, ln1_g + blk * DD, ln1_b + blk * DD, xnf, 1);

        gemm_qkv<<<dim3(MM / 128, 6), 256, 0, stream>>>(
            (const bf16x8*)xnf, (const bf16x8*)ctxf,
            (const bf16x8*)(WQF + blk * 65536), (const bf16x8*)(KVF + blk * 131072),
            qbuf, kvbuf);

        attn_kernel<<<MM / 4, 256, 0, stream>>>(qbuf, kvbuf, coord_a, ccrd, knn,
                                                pe_w + blk * 3 * DD, pe_b + blk * DD, attnf);

        gemm_frag<256, 256, GOUT_F32, true, false><<<dim3(MM / 128, 2), 256, 0, stream>>>(
            (const bf16x8*)attnf, (const bf16x8*)(WOF + blk * 65536), xmid, x_in, nullptr, 0);

        ln_to_frag<<<MM / 4, 256, 0, stream>>>(xmid, ln2_g + blk * DD, ln2_b + blk * DD, xnf, 1);

        gemm_frag<256, 1024, GOUT_GELU_FRAG, false, true><<<dim3(MM / 128, 8), 256, 0, stream>>>(
            (const bf16x8*)xnf, (const bf16x8*)(W1F + blk * 262144), geluf, nullptr,
            b1 + blk * DFF_, 1024);

        gemm_frag<1024, 256, GOUT_F32, true, true><<<dim3(MM / 128, 2), 256, 0, stream>>>(
            (const bf16x8*)geluf, (const bf16x8*)(W2F + blk * 262144), x_out_final, xmid,
            b2 + blk * DD, 0);
    }
}